// Round 16
// baseline (255.482 us; speedup 1.0000x reference)
//
#include <hip/hip_runtime.h>
#include <stdint.h>

typedef unsigned short u16;
typedef __bf16  bf16x8 __attribute__((ext_vector_type(8), may_alias));
typedef u16     u16x8  __attribute__((ext_vector_type(8), may_alias));
typedef float   f32x4  __attribute__((ext_vector_type(4)));
typedef float   f32x4u __attribute__((ext_vector_type(4), may_alias));

#define Bv   2
#define Sv   2048
#define Dv   2048
#define Hv   16
#define KVHv 4
#define HDv  128
#define Tv   (Bv*Sv)      // 4096 tokens
#define QKVN 3072         // 2048 Q + 512 K + 512 V
#define MAXROWS 4352      // 17 tiles of 256 (worst-case padded segments)

__device__ __forceinline__ float b2f(u16 u) {
    union { float f; uint32_t i; } x; x.i = ((uint32_t)u) << 16; return x.f;
}
__device__ __forceinline__ u16 f2b(float f) {
    union { float f; uint32_t u; } x; x.f = f;
    uint32_t r = x.u + 0x7fff + ((x.u >> 16) & 1);
    return (u16)(r >> 16);
}
// global -> LDS direct (16B per lane; LDS dest wave-uniform base, HW adds lane*16)
__device__ __forceinline__ void gload_lds16(const void* g, void* l) {
    __builtin_amdgcn_global_load_lds((__attribute__((address_space(1))) void*)(uintptr_t)g,
                                     (__attribute__((address_space(3))) void*)(uintptr_t)l,
                                     16, 0, 0);
}

// ---------- stable modality compaction (segments padded to 256 rows) ----------
__global__ __launch_bounds__(1024) void scan_mod(const int* __restrict__ mod, int* __restrict__ fwd,
                                                 int* __restrict__ inv, int* __restrict__ hdr) {
    __shared__ int cnt[1024];
    const int tid = threadIdx.x;
    int m[4]; int c = 0;
#pragma unroll
    for (int e = 0; e < 4; ++e) { m[e] = mod[tid * 4 + e]; c += (m[e] == 0); }
    cnt[tid] = c;
    __syncthreads();
    for (int off = 1; off < 1024; off <<= 1) {
        int v = (tid >= off) ? cnt[tid - off] : 0;
        __syncthreads();
        cnt[tid] += v;
        __syncthreads();
    }
    const int c0 = cnt[1023];
    const int c0pad = (c0 + 255) & ~255;
    const int c1 = Tv - c0;
    const int total = c0pad + ((c1 + 255) & ~255);
    for (int p = tid; p < MAXROWS; p += 1024) inv[p] = -1;
    __syncthreads();
    const int ex0 = cnt[tid] - c;            // mod-0 tokens before this chunk
    int z = 0;
#pragma unroll
    for (int e = 0; e < 4; ++e) {
        int t = tid * 4 + e;
        int pos;
        if (m[e] == 0) { pos = ex0 + z; ++z; }
        else           { pos = c0pad + (t - (ex0 + z)); }
        fwd[t] = pos;
        inv[pos] = t;
    }
    if (tid == 0) { hdr[0] = total >> 8; hdr[1] = c0pad; hdr[2] = total; }
}

// ---------- gather + cast: Xg[pos] = bf16(x[inv[pos]]) or 0 ----------
__global__ void gather_cast(const float* __restrict__ x, const int* __restrict__ inv,
                            u16* __restrict__ Xg) {
    int v = blockIdx.x * 256 + threadIdx.x;
    int pos = v >> 8, c8 = (v & 255) * 8;
    int t = inv[pos];
    u16x8 val = {0, 0, 0, 0, 0, 0, 0, 0};
    if (t >= 0) {
        f32x4u a = *(const f32x4u*)&x[(size_t)t * Dv + c8];
        f32x4u b = *(const f32x4u*)&x[(size_t)t * Dv + c8 + 4];
#pragma unroll
        for (int j = 0; j < 4; ++j) { val[j] = f2b(a[j]); val[4 + j] = f2b(b[j]); }
    }
    *(u16x8*)&Xg[(size_t)pos * Dv + c8] = val;
}

// ---------- fused transpose + cast f32->bf16 for all 4 weights (one launch) ----------
__global__ void transpose_all(const float* __restrict__ wq, const float* __restrict__ wk,
                              const float* __restrict__ wv, const float* __restrict__ wo,
                              u16* __restrict__ Wqkv_t, u16* __restrict__ Wo_t) {
    const int id = blockIdx.x;
    const float* in; u16* out; int C; size_t inZ, outZ; int bx, by, z;
    if (id < 2048)      { int l = id;        in = wq; out = Wqkv_t;                     C = 2048; inZ = (size_t)2048 * 2048; outZ = (size_t)3072 * 2048; bx = l & 31; by = (l >> 5) & 31; z = l >> 10; }
    else if (id < 2560) { int l = id - 2048; in = wk; out = Wqkv_t + (size_t)2048 * 2048; C = 512;  inZ = (size_t)2048 * 512;  outZ = (size_t)3072 * 2048; bx = l & 7;  by = (l >> 3) & 31; z = l >> 8; }
    else if (id < 3072) { int l = id - 2560; in = wv; out = Wqkv_t + (size_t)2560 * 2048; C = 512;  inZ = (size_t)2048 * 512;  outZ = (size_t)3072 * 2048; bx = l & 7;  by = (l >> 3) & 31; z = l >> 8; }
    else                { int l = id - 3072; in = wo; out = Wo_t;                       C = 2048; inZ = (size_t)2048 * 2048; outZ = (size_t)2048 * 2048; bx = l & 31; by = (l >> 5) & 31; z = l >> 10; }
    in  += (size_t)z * inZ;
    out += (size_t)z * outZ;
    __shared__ u16 tile[64][72];
    const int tr = by * 64, tc = bx * 64;
    const int tid = threadIdx.x;
#pragma unroll
    for (int i = 0; i < 4; ++i) {
        int s = tid + 256 * i;
        int r = s >> 4, c4 = (s & 15) * 4;
        f32x4u v = *(const f32x4u*)&in[(size_t)(tr + r) * C + tc + c4];
#pragma unroll
        for (int j = 0; j < 4; ++j) tile[r][c4 + j] = f2b(v[j]);
    }
    __syncthreads();
#pragma unroll
    for (int i = 0; i < 2; ++i) {
        int s = tid + 256 * i;
        int r = s >> 3, c8 = (s & 7) * 8;
        u16x8 v;
#pragma unroll
        for (int j = 0; j < 8; ++j) v[j] = tile[c8 + j][r];
        *(u16x8*)&out[(size_t)(tc + r) * 2048 + tr + c8] = v;
    }
}

__device__ __forceinline__ void store_c(u16* C, size_t idx, float v) { C[idx] = f2b(v); }
__device__ __forceinline__ void store_c(float* C, size_t idx, float v) { C[idx] = v; }

// ---------- 256x256 segmented GEMM, 8 waves, counted-vmcnt 4-phase pipeline ----------
// ROPE=true (QKV gemm): epilogue applies RoPE to cols<2560 in-register. The pair (2i,2i+1)
// sits in adjacent l15 lanes -> partner via shfl_xor(v,1); cos/sin from the L2-resident fc
// table; Q-scale rsqrt(128)*log2e folded (exp2-domain softmax downstream). V cols untouched.
template <typename OutT, bool ROPE>
__global__ __launch_bounds__(512, 2) void gemm256(const u16* __restrict__ A,
                                                  const u16* __restrict__ Bt,
                                                  OutT* __restrict__ C,
                                                  const int* __restrict__ inv,
                                                  const int* __restrict__ hdr,
                                                  const float* __restrict__ fc,
                                                  int Nfull, int ldC) {
    const int total = hdr[2], c0pad = hdr[1];
    const int bm = blockIdx.y * 256;
    if (bm >= total) return;
    const u16* B = Bt + (size_t)((bm >= c0pad) ? 1 : 0) * Nfull * 2048;
    const int bn = blockIdx.x * 256;
    const int tid = threadIdx.x;
    const int wave = tid >> 6, lane = tid & 63;
    const int l15 = lane & 15, l4 = lane >> 4;
    const int wm = wave >> 2;
    const int wn = wave & 3;
    const int bhh = wn >> 1, brr = (wn & 1) * 64;
    const int rsw = l15 & 7;
    __shared__ u16 ldsA[2][2][128 * 64];
    __shared__ u16 ldsB[2][2][128 * 64];
    const int srow = tid >> 3;
    const int ssw  = (tid & 7) ^ (srow & 7);
    const int wofs = wave * 8 * 64;

    f32x4 acc[8][4] = {};

    auto stA = [&](int sl, int h, int jrb, int kt) {
        gload_lds16(A + (size_t)(bm + h * 128 + jrb * 64 + srow) * 2048 + kt * 64 + ssw * 8,
                    &ldsA[sl][h][jrb * 64 * 64 + wofs]);
    };
    auto stB = [&](int sl, int h, int jrb, int kt) {
        gload_lds16(B + (size_t)(bn + h * 128 + jrb * 64 + srow) * 2048 + kt * 64 + ssw * 8,
                    &ldsB[sl][h][jrb * 64 * 64 + wofs]);
    };

    stB(0, 0, 0, 0); stB(0, 0, 1, 0); stB(0, 1, 0, 0); stB(0, 1, 1, 0);
    stA(0, 0, 0, 0); stA(0, 1, 0, 0); stA(0, 0, 1, 0); stA(0, 1, 1, 0);
    asm volatile("s_waitcnt vmcnt(2)" ::: "memory");
    __builtin_amdgcn_s_barrier();
    __builtin_amdgcn_sched_barrier(0);

    for (int kt = 0; kt < 32; ++kt) {
        const int s = kt & 1;
        const bool st = (kt < 31);
        bf16x8 bfr[4][2];
#pragma unroll
        for (int fj = 0; fj < 4; ++fj)
#pragma unroll
            for (int kc = 0; kc < 2; ++kc)
                bfr[fj][kc] = *(const bf16x8*)&ldsB[s][bhh][(brr + fj * 16 + l15) * 64 + ((kc * 4 + l4) ^ rsw) * 8];
#pragma unroll
        for (int q = 0; q < 4; ++q) {
            bf16x8 af[2][2];
#pragma unroll
            for (int fi = 0; fi < 2; ++fi)
#pragma unroll
                for (int kc = 0; kc < 2; ++kc)
                    af[fi][kc] = *(const bf16x8*)&ldsA[s][wm][(q * 32 + fi * 16 + l15) * 64 + ((kc * 4 + l4) ^ rsw) * 8];
            if (st) {
                if      (q == 0) { stB(s ^ 1, 0, 0, kt + 1); stB(s ^ 1, 0, 1, kt + 1); }
                else if (q == 1) { stB(s ^ 1, 1, 0, kt + 1); stB(s ^ 1, 1, 1, kt + 1); }
                else if (q == 2) { stA(s ^ 1, 0, 0, kt + 1); stA(s ^ 1, 1, 0, kt + 1); }
                else             { stA(s ^ 1, 0, 1, kt + 1); stA(s ^ 1, 1, 1, kt + 1); }
            }
            __builtin_amdgcn_s_setprio(1);
#pragma unroll
            for (int kc = 0; kc < 2; ++kc)
#pragma unroll
                for (int fi = 0; fi < 2; ++fi)
#pragma unroll
                    for (int fj = 0; fj < 4; ++fj)
                        acc[q * 2 + fi][fj] = __builtin_amdgcn_mfma_f32_16x16x32_bf16(
                            af[fi][kc], bfr[fj][kc], acc[q * 2 + fi][fj], 0, 0, 0);
            __builtin_amdgcn_s_setprio(0);
            if (q == 1) {
                if (st) asm volatile("s_waitcnt vmcnt(4)" ::: "memory");
                else    asm volatile("s_waitcnt vmcnt(0)" ::: "memory");
                __builtin_amdgcn_sched_barrier(0);
            }
            if (q == 3 && st) {
                asm volatile("s_waitcnt vmcnt(2)" ::: "memory");
                __builtin_amdgcn_sched_barrier(0);
            }
            __builtin_amdgcn_s_barrier();
            __builtin_amdgcn_sched_barrier(0);
        }
    }
#pragma unroll
    for (int fi = 0; fi < 8; ++fi)
#pragma unroll
        for (int r = 0; r < 4; ++r) {
            int row = bm + wm * 128 + fi * 16 + l4 * 4 + r;
            int t = inv[row];           // uniform across l15 (row indep of l15) -> shfl safe
            if (t >= 0) {
#pragma unroll
                for (int fj = 0; fj < 4; ++fj) {
                    int col = bn + wn * 64 + fj * 16 + l15;
                    float v = acc[fi][fj][r];
                    if constexpr (ROPE) {
                        if (col < 2560) {   // uniform per fj-tile (region boundaries are x16)
                            float pr = __shfl_xor(v, 1, 64);   // partner lane l15^1 = col^1
                            f32x4u f = *(const f32x4u*)&fc[((size_t)(t & (Sv - 1)) * 64 + ((col & 127) >> 1)) * 4];
                            float sc = (col < 2048) ? 0.12751742f : 1.0f;  // rsqrt(128)*log2e on Q
                            v = (col & 1) ? (f[2] * pr + f[0] * v) * sc
                                          : (f[0] * v - f[2] * pr) * sc;
                        }
                    }
                    store_c(C, (size_t)t * ldC + col, v);
                }
            }
        }
}

// ---------- causal GQA flash attention (R13 structure: paired q-tiles, uniform work) ----------
// 8 waves: group 0 (waves 0-3) owns 64-row q-tile p, group 1 owns 31-p -> every block does
// exactly 32 stages + 33 group-computes (scheduler-independent balance, 2 blocks/CU).
// Swapped QK (q=l15) + permuted K rows (kv'(p) = (p&32)|((p&12)<<1)|((p&16)>>2)|(p&3)) so
// sacc[nt][r] = P[q][kv=(nt>>1)*32+l4*8+(nt&1)*4+r]; P-frags via 8x cvt_pk (no cross-lane).
// PV fully swapped -> O^T; transposed once in LDS epilogue. exp2-domain softmax.
// T5 setprio around MFMA clusters; T13 defer-max (THR=8).
__global__ __launch_bounds__(512) void attn_fwd(const u16* __restrict__ QKV, u16* __restrict__ Ag,
                                                const int* __restrict__ fwd) {
    const int p = blockIdx.x;                 // pair id 0..15
    const int h = blockIdx.y, b = blockIdx.z;
    const int kvh = h >> 2;
    const int tid = threadIdx.x, wave = tid >> 6, lane = tid & 63;
    const int wgrp = wave >> 2, wl = wave & 3;
    const int l15 = lane & 15, l4 = lane >> 4;
    const int myqb = wgrp ? (31 - p) : p;
    __shared__ u16 smem[32768];               // K dbuf @0/@8192, V dbuf @16384/@24576

    bf16x8 qf[4];
    {
        const size_t qrow = (size_t)(b * Sv + myqb * 64 + wl * 16 + l15);
#pragma unroll
        for (int kc = 0; kc < 4; ++kc)
            qf[kc] = *(const bf16x8*)&QKV[qrow * QKVN + h * 128 + kc * 32 + l4 * 8];
    }
    f32x4 oacc[8] = {};
    float mrow = -1e30f;   // running max (log2 domain) for q = l15
    float lrow = 0.f;

    const size_t kvbase = (size_t)b * Sv * QKVN + 2048 + kvh * 128;

    // ---- prologue: stage tile 0 ----
    {
#pragma unroll
        for (int i = 0; i < 2; ++i) {
            int s_u = wave * 64 + 512 * i;
            int s = s_u + lane;
            int r = s >> 4;                                   // LDS row
            int kvsrc = (r & 32) | ((r & 12) << 1) | ((r & 16) >> 2) | (r & 3);
            int cs = (s & 15) ^ (r & 7);
            gload_lds16(QKV + kvbase + (size_t)kvsrc * QKVN + cs * 8, &smem[(size_t)s_u * 8]);
        }
        u16x8 vr0 = *(const u16x8*)&QKV[kvbase + 512 + (size_t)lane * QKVN + (0 * 8 + wave) * 8];
        u16x8 vr1 = *(const u16x8*)&QKV[kvbase + 512 + (size_t)lane * QKVN + (1 * 8 + wave) * 8];
#pragma unroll
        for (int jj = 0; jj < 8; ++jj) {
            int d0 = wave * 8 + jj, d1 = (8 + wave) * 8 + jj;
            smem[16384 + d0 * 64 + ((((lane >> 3) ^ jj) << 3) | (lane & 7))] = vr0[jj];
            smem[16384 + d1 * 64 + ((((lane >> 3) ^ jj) << 3) | (lane & 7))] = vr1[jj];
        }
    }
    __syncthreads();

    for (int j = 0; j < 32; ++j) {
        const int cur = j & 1;
        const bool stage_next = (j < 31);
        u16* Kcur = smem + cur * 8192;
        u16* Knxt = smem + (cur ^ 1) * 8192;
        u16* Vcur = smem + 16384 + cur * 8192;
        u16* Vnxt = smem + 16384 + (cur ^ 1) * 8192;
        u16x8 vn0, vn1;
        if (stage_next) {
            const size_t nb = kvbase + (size_t)(j + 1) * 64 * QKVN;
#pragma unroll
            for (int i = 0; i < 2; ++i) {
                int s_u = wave * 64 + 512 * i;
                int s = s_u + lane;
                int r = s >> 4;
                int kvsrc = (r & 32) | ((r & 12) << 1) | ((r & 16) >> 2) | (r & 3);
                int cs = (s & 15) ^ (r & 7);
                gload_lds16(QKV + nb + (size_t)kvsrc * QKVN + cs * 8, &Knxt[(size_t)s_u * 8]);
            }
            vn0 = *(const u16x8*)&QKV[nb + 512 + (size_t)lane * QKVN + (0 * 8 + wave) * 8];
            vn1 = *(const u16x8*)&QKV[nb + 512 + (size_t)lane * QKVN + (1 * 8 + wave) * 8];
        }
        if (j <= myqb) {
            f32x4 sacc[4] = {};
            __builtin_amdgcn_s_setprio(1);
#pragma unroll
            for (int kc = 0; kc < 4; ++kc)
#pragma unroll
                for (int nt = 0; nt < 4; ++nt) {
                    int cs = ((kc * 4 + l4) ^ (l15 & 7));
                    bf16x8 kf = *(const bf16x8*)&Kcur[(nt * 16 + l15) * 128 + cs * 8];
                    sacc[nt] = __builtin_amdgcn_mfma_f32_16x16x32_bf16(kf, qf[kc], sacc[nt], 0, 0, 0);
                }
            __builtin_amdgcn_s_setprio(0);
            if (j == myqb) {
                // actual kv for sacc[nt][r] = (nt>>1)*32 + l4*8 + (nt&1)*4 + r
#pragma unroll
                for (int nt = 0; nt < 4; ++nt)
#pragma unroll
                    for (int r = 0; r < 4; ++r)
                        if ((nt >> 1) * 32 + l4 * 8 + (nt & 1) * 4 + r > wl * 16 + l15)
                            sacc[nt][r] = -1e30f;
            }
            // ---- lane-local online softmax (log2 domain) for q = l15 ----
            f32x4 mv = sacc[0];
#pragma unroll
            for (int nt = 1; nt < 4; ++nt)
#pragma unroll
                for (int r = 0; r < 4; ++r) mv[r] = fmaxf(mv[r], sacc[nt][r]);
            float mx = fmaxf(fmaxf(mv[0], mv[1]), fmaxf(mv[2], mv[3]));
            mx = fmaxf(mx, __shfl_xor(mx, 16, 64));
            mx = fmaxf(mx, __shfl_xor(mx, 32, 64));
            const bool defer = __all(mx <= mrow + 8.0f);
            if (!defer) {
                float mnew = fmaxf(mrow, mx);
                float fs = exp2f(mrow - mnew);
                mrow = mnew;
                lrow *= fs;
#pragma unroll
                for (int nt = 0; nt < 8; ++nt)
#pragma unroll
                    for (int r = 0; r < 4; ++r) oacc[nt][r] *= fs;
            }
            f32x4 pv = {0.f, 0.f, 0.f, 0.f};
#pragma unroll
            for (int nt = 0; nt < 4; ++nt)
#pragma unroll
                for (int r = 0; r < 4; ++r) {
                    float pe = exp2f(sacc[nt][r] - mrow);
                    sacc[nt][r] = pe;
                    pv[r] += pe;
                }
            float ps = (pv[0] + pv[1]) + (pv[2] + pv[3]);
            ps += __shfl_xor(ps, 16, 64);
            ps += __shfl_xor(ps, 32, 64);
            lrow += ps;
            // ---- P fragments in-register: 8x cvt_pk, zero cross-lane ----
            union { uint32_t w[4]; bf16x8 v; } pb0u, pb1u;
#pragma unroll
            for (int nt = 0; nt < 2; ++nt) {
                asm("v_cvt_pk_bf16_f32 %0, %1, %2" : "=v"(pb0u.w[nt * 2])     : "v"(sacc[nt][0]), "v"(sacc[nt][1]));
                asm("v_cvt_pk_bf16_f32 %0, %1, %2" : "=v"(pb0u.w[nt * 2 + 1]) : "v"(sacc[nt][2]), "v"(sacc[nt][3]));
                asm("v_cvt_pk_bf16_f32 %0, %1, %2" : "=v"(pb1u.w[nt * 2])     : "v"(sacc[nt + 2][0]), "v"(sacc[nt + 2][1]));
                asm("v_cvt_pk_bf16_f32 %0, %1, %2" : "=v"(pb1u.w[nt * 2 + 1]) : "v"(sacc[nt + 2][2]), "v"(sacc[nt + 2][3]));
            }
            bf16x8 pb0 = pb0u.v, pb1 = pb1u.v;
            // ---- PV: O^T += V^T * P^T ----
            __builtin_amdgcn_s_setprio(1);
#pragma unroll
            for (int nt = 0; nt < 8; ++nt) {
                int d = nt * 16 + l15;           // d&7 == l15&7
                bf16x8 v0 = *(const bf16x8*)&Vcur[d * 64 + ((l4 ^ (l15 & 7)) << 3)];
                bf16x8 v1 = *(const bf16x8*)&Vcur[d * 64 + (((4 + l4) ^ (l15 & 7)) << 3)];
                oacc[nt] = __builtin_amdgcn_mfma_f32_16x16x32_bf16(v0, pb0, oacc[nt], 0, 0, 0);
                oacc[nt] = __builtin_amdgcn_mfma_f32_16x16x32_bf16(v1, pb1, oacc[nt], 0, 0, 0);
            }
            __builtin_amdgcn_s_setprio(0);
        }
        if (stage_next) {
#pragma unroll
            for (int jj = 0; jj < 8; ++jj) {
                int d0 = wave * 8 + jj, d1 = (8 + wave) * 8 + jj;
                Vnxt[d0 * 64 + ((((lane >> 3) ^ jj) << 3) | (lane & 7))] = vn0[jj];
                Vnxt[d1 * 64 + ((((lane >> 3) ^ jj) << 3) | (lane & 7))] = vn1[jj];
            }
        }
        __syncthreads();
    }
    // ---- epilogue: transpose O^T -> token-major via per-wave LDS (K/V buffers dead) ----
    {
        u16* epi = smem + wave * (16 * 136);   // [16 q][128 d + 8 pad]
        float rinv = 1.0f / lrow;              // per lane q=l15
#pragma unroll
        for (int nt = 0; nt < 8; ++nt)
#pragma unroll
            for (int r = 0; r < 4; ++r)
                epi[l15 * 136 + nt * 16 + l4 * 4 + r] = f2b(oacc[nt][r] * rinv);
        const int q = lane >> 2;
        const int rowmap = fwd[b * Sv + myqb * 64 + wl * 16 + q];
#pragma unroll
        for (int it = 0; it < 4; ++it) {
            int dv = (lane & 3) + it * 4;
            u16x8 v = *(const u16x8*)&epi[q * 136 + dv * 8];
            *(u16x8*)&Ag[(size_t)rowmap * 2048 + h * 128 + dv * 8] = v;
        }
    }
}

extern "C" void kernel_launch(void* const* d_in, const int* in_sizes, int n_in,
                              void* d_out, int out_size, void* d_ws, size_t ws_size,
                              hipStream_t stream) {
    const float* x   = (const float*)d_in[0];
    const float* fc  = (const float*)d_in[1];
    const int*   mod = (const int*)d_in[2];
    const float* wq  = (const float*)d_in[3];
    const float* wk  = (const float*)d_in[4];
    const float* wv  = (const float*)d_in[5];
    const float* wo  = (const float*)d_in[6];
    float* out = (float*)d_out;
    char* ws = (char*)d_ws;
    u16* Wqkv_t = (u16*)(ws);               // 2 x (3072 x 2048) bf16 = 25,165,824
    u16* Wo_t   = (u16*)(ws + 25165824);    // 2 x (2048 x 2048) bf16 = 16,777,216
    u16* Xg     = (u16*)(ws + 41943040);    // MAXROWS x 2048 bf16 = 17,825,792 (reused as Ag)
    u16* QKV    = (u16*)(ws + 59768832);    // 4096 x 3072 bf16 = 25,165,824
    int* fwd    = (int*)(ws + 84934656);    // 4096 ints
    int* inv    = (int*)(ws + 84951040);    // MAXROWS ints
    int* hdr    = (int*)(ws + 84968448);    // small header
    u16* Ag     = Xg;                        // Xg dead after QKV GEMM; pads stay zero from gather_cast

    transpose_all<<<5120, 256, 0, stream>>>(wq, wk, wv, wo, Wqkv_t, Wo_t);
    scan_mod<<<1, 1024, 0, stream>>>(mod, fwd, inv, hdr);
    gather_cast<<<MAXROWS, 256, 0, stream>>>(x, inv, Xg);
    // QKV GEMM with fused RoPE epilogue (rope_kernel eliminated)
    gemm256<u16, true><<<dim3(12, 17), 512, 0, stream>>>(Xg, Wqkv_t, QKV, inv, hdr, fc, 3072, 3072);
    attn_fwd<<<dim3(16, 16, 2), 512, 0, stream>>>(QKV, Ag, fwd);
    gemm256<float, false><<<dim3(8, 17), 512, 0, stream>>>(Ag, Wo_t, out, inv, hdr, nullptr, 2048, 2048);
}

// Round 17
// 227.716 us; speedup vs baseline: 1.1219x; 1.1219x over previous
//
#include <hip/hip_runtime.h>
#include <stdint.h>

typedef unsigned short u16;
typedef __bf16  bf16x8 __attribute__((ext_vector_type(8), may_alias));
typedef u16     u16x8  __attribute__((ext_vector_type(8), may_alias));
typedef float   f32x4  __attribute__((ext_vector_type(4)));
typedef float   f32x4u __attribute__((ext_vector_type(4), may_alias));

#define Bv   2
#define Sv   2048
#define Dv   2048
#define Hv   16
#define KVHv 4
#define HDv  128
#define Tv   (Bv*Sv)      // 4096 tokens
#define QKVN 3072         // 2048 Q + 512 K + 512 V
#define MAXROWS 4352      // 17 tiles of 256 (worst-case padded segments)

__device__ __forceinline__ float b2f(u16 u) {
    union { float f; uint32_t i; } x; x.i = ((uint32_t)u) << 16; return x.f;
}
__device__ __forceinline__ u16 f2b(float f) {
    union { float f; uint32_t u; } x; x.f = f;
    uint32_t r = x.u + 0x7fff + ((x.u >> 16) & 1);
    return (u16)(r >> 16);
}
// global -> LDS direct (16B per lane; LDS dest wave-uniform base, HW adds lane*16)
__device__ __forceinline__ void gload_lds16(const void* g, void* l) {
    __builtin_amdgcn_global_load_lds((__attribute__((address_space(1))) void*)(uintptr_t)g,
                                     (__attribute__((address_space(3))) void*)(uintptr_t)l,
                                     16, 0, 0);
}

// ---------- stable modality compaction (segments padded to 256 rows) ----------
__global__ __launch_bounds__(1024) void scan_mod(const int* __restrict__ mod, int* __restrict__ fwd,
                                                 int* __restrict__ inv, int* __restrict__ hdr) {
    __shared__ int cnt[1024];
    const int tid = threadIdx.x;
    int m[4]; int c = 0;
#pragma unroll
    for (int e = 0; e < 4; ++e) { m[e] = mod[tid * 4 + e]; c += (m[e] == 0); }
    cnt[tid] = c;
    __syncthreads();
    for (int off = 1; off < 1024; off <<= 1) {
        int v = (tid >= off) ? cnt[tid - off] : 0;
        __syncthreads();
        cnt[tid] += v;
        __syncthreads();
    }
    const int c0 = cnt[1023];
    const int c0pad = (c0 + 255) & ~255;
    const int c1 = Tv - c0;
    const int total = c0pad + ((c1 + 255) & ~255);
    for (int p = tid; p < MAXROWS; p += 1024) inv[p] = -1;
    __syncthreads();
    const int ex0 = cnt[tid] - c;            // mod-0 tokens before this chunk
    int z = 0;
#pragma unroll
    for (int e = 0; e < 4; ++e) {
        int t = tid * 4 + e;
        int pos;
        if (m[e] == 0) { pos = ex0 + z; ++z; }
        else           { pos = c0pad + (t - (ex0 + z)); }
        fwd[t] = pos;
        inv[pos] = t;
    }
    if (tid == 0) { hdr[0] = total >> 8; hdr[1] = c0pad; hdr[2] = total; }
}

// ---------- gather + cast: Xg[pos] = bf16(x[inv[pos]]) or 0 ----------
__global__ void gather_cast(const float* __restrict__ x, const int* __restrict__ inv,
                            u16* __restrict__ Xg) {
    int v = blockIdx.x * 256 + threadIdx.x;
    int pos = v >> 8, c8 = (v & 255) * 8;
    int t = inv[pos];
    u16x8 val = {0, 0, 0, 0, 0, 0, 0, 0};
    if (t >= 0) {
        f32x4u a = *(const f32x4u*)&x[(size_t)t * Dv + c8];
        f32x4u b = *(const f32x4u*)&x[(size_t)t * Dv + c8 + 4];
#pragma unroll
        for (int j = 0; j < 4; ++j) { val[j] = f2b(a[j]); val[4 + j] = f2b(b[j]); }
    }
    *(u16x8*)&Xg[(size_t)pos * Dv + c8] = val;
}

// ---------- fused transpose + cast f32->bf16 for all 4 weights (one launch) ----------
__global__ void transpose_all(const float* __restrict__ wq, const float* __restrict__ wk,
                              const float* __restrict__ wv, const float* __restrict__ wo,
                              u16* __restrict__ Wqkv_t, u16* __restrict__ Wo_t) {
    const int id = blockIdx.x;
    const float* in; u16* out; int C; size_t inZ, outZ; int bx, by, z;
    if (id < 2048)      { int l = id;        in = wq; out = Wqkv_t;                     C = 2048; inZ = (size_t)2048 * 2048; outZ = (size_t)3072 * 2048; bx = l & 31; by = (l >> 5) & 31; z = l >> 10; }
    else if (id < 2560) { int l = id - 2048; in = wk; out = Wqkv_t + (size_t)2048 * 2048; C = 512;  inZ = (size_t)2048 * 512;  outZ = (size_t)3072 * 2048; bx = l & 7;  by = (l >> 3) & 31; z = l >> 8; }
    else if (id < 3072) { int l = id - 2560; in = wv; out = Wqkv_t + (size_t)2560 * 2048; C = 512;  inZ = (size_t)2048 * 512;  outZ = (size_t)3072 * 2048; bx = l & 7;  by = (l >> 3) & 31; z = l >> 8; }
    else                { int l = id - 3072; in = wo; out = Wo_t;                       C = 2048; inZ = (size_t)2048 * 2048; outZ = (size_t)2048 * 2048; bx = l & 31; by = (l >> 5) & 31; z = l >> 10; }
    in  += (size_t)z * inZ;
    out += (size_t)z * outZ;
    __shared__ u16 tile[64][72];
    const int tr = by * 64, tc = bx * 64;
    const int tid = threadIdx.x;
#pragma unroll
    for (int i = 0; i < 4; ++i) {
        int s = tid + 256 * i;
        int r = s >> 4, c4 = (s & 15) * 4;
        f32x4u v = *(const f32x4u*)&in[(size_t)(tr + r) * C + tc + c4];
#pragma unroll
        for (int j = 0; j < 4; ++j) tile[r][c4 + j] = f2b(v[j]);
    }
    __syncthreads();
#pragma unroll
    for (int i = 0; i < 2; ++i) {
        int s = tid + 256 * i;
        int r = s >> 3, c8 = (s & 7) * 8;
        u16x8 v;
#pragma unroll
        for (int j = 0; j < 8; ++j) v[j] = tile[c8 + j][r];
        *(u16x8*)&out[(size_t)(tc + r) * 2048 + tr + c8] = v;
    }
}

__device__ __forceinline__ void store_c(u16* C, size_t idx, float v) { C[idx] = f2b(v); }
__device__ __forceinline__ void store_c(float* C, size_t idx, float v) { C[idx] = v; }

// ---------- 256x256 segmented GEMM, 8 waves, counted-vmcnt 4-phase pipeline ----------
template <typename OutT>
__global__ __launch_bounds__(512, 2) void gemm256(const u16* __restrict__ A,
                                                  const u16* __restrict__ Bt,
                                                  OutT* __restrict__ C,
                                                  const int* __restrict__ inv,
                                                  const int* __restrict__ hdr,
                                                  int Nfull, int ldC) {
    const int total = hdr[2], c0pad = hdr[1];
    const int bm = blockIdx.y * 256;
    if (bm >= total) return;
    const u16* B = Bt + (size_t)((bm >= c0pad) ? 1 : 0) * Nfull * 2048;
    const int bn = blockIdx.x * 256;
    const int tid = threadIdx.x;
    const int wave = tid >> 6, lane = tid & 63;
    const int l15 = lane & 15, l4 = lane >> 4;
    const int wm = wave >> 2;
    const int wn = wave & 3;
    const int bhh = wn >> 1, brr = (wn & 1) * 64;
    const int rsw = l15 & 7;
    __shared__ u16 ldsA[2][2][128 * 64];
    __shared__ u16 ldsB[2][2][128 * 64];
    const int srow = tid >> 3;
    const int ssw  = (tid & 7) ^ (srow & 7);
    const int wofs = wave * 8 * 64;

    f32x4 acc[8][4] = {};

    auto stA = [&](int sl, int h, int jrb, int kt) {
        gload_lds16(A + (size_t)(bm + h * 128 + jrb * 64 + srow) * 2048 + kt * 64 + ssw * 8,
                    &ldsA[sl][h][jrb * 64 * 64 + wofs]);
    };
    auto stB = [&](int sl, int h, int jrb, int kt) {
        gload_lds16(B + (size_t)(bn + h * 128 + jrb * 64 + srow) * 2048 + kt * 64 + ssw * 8,
                    &ldsB[sl][h][jrb * 64 * 64 + wofs]);
    };

    stB(0, 0, 0, 0); stB(0, 0, 1, 0); stB(0, 1, 0, 0); stB(0, 1, 1, 0);
    stA(0, 0, 0, 0); stA(0, 1, 0, 0); stA(0, 0, 1, 0); stA(0, 1, 1, 0);
    asm volatile("s_waitcnt vmcnt(2)" ::: "memory");
    __builtin_amdgcn_s_barrier();
    __builtin_amdgcn_sched_barrier(0);

    for (int kt = 0; kt < 32; ++kt) {
        const int s = kt & 1;
        const bool st = (kt < 31);
        bf16x8 bfr[4][2];
#pragma unroll
        for (int fj = 0; fj < 4; ++fj)
#pragma unroll
            for (int kc = 0; kc < 2; ++kc)
                bfr[fj][kc] = *(const bf16x8*)&ldsB[s][bhh][(brr + fj * 16 + l15) * 64 + ((kc * 4 + l4) ^ rsw) * 8];
#pragma unroll
        for (int q = 0; q < 4; ++q) {
            bf16x8 af[2][2];
#pragma unroll
            for (int fi = 0; fi < 2; ++fi)
#pragma unroll
                for (int kc = 0; kc < 2; ++kc)
                    af[fi][kc] = *(const bf16x8*)&ldsA[s][wm][(q * 32 + fi * 16 + l15) * 64 + ((kc * 4 + l4) ^ rsw) * 8];
            if (st) {
                if      (q == 0) { stB(s ^ 1, 0, 0, kt + 1); stB(s ^ 1, 0, 1, kt + 1); }
                else if (q == 1) { stB(s ^ 1, 1, 0, kt + 1); stB(s ^ 1, 1, 1, kt + 1); }
                else if (q == 2) { stA(s ^ 1, 0, 0, kt + 1); stA(s ^ 1, 1, 0, kt + 1); }
                else             { stA(s ^ 1, 0, 1, kt + 1); stA(s ^ 1, 1, 1, kt + 1); }
            }
            __builtin_amdgcn_s_setprio(1);
#pragma unroll
            for (int kc = 0; kc < 2; ++kc)
#pragma unroll
                for (int fi = 0; fi < 2; ++fi)
#pragma unroll
                    for (int fj = 0; fj < 4; ++fj)
                        acc[q * 2 + fi][fj] = __builtin_amdgcn_mfma_f32_16x16x32_bf16(
                            af[fi][kc], bfr[fj][kc], acc[q * 2 + fi][fj], 0, 0, 0);
            __builtin_amdgcn_s_setprio(0);
            if (q == 1) {
                if (st) asm volatile("s_waitcnt vmcnt(4)" ::: "memory");
                else    asm volatile("s_waitcnt vmcnt(0)" ::: "memory");
                __builtin_amdgcn_sched_barrier(0);
            }
            if (q == 3 && st) {
                asm volatile("s_waitcnt vmcnt(2)" ::: "memory");
                __builtin_amdgcn_sched_barrier(0);
            }
            __builtin_amdgcn_s_barrier();
            __builtin_amdgcn_sched_barrier(0);
        }
    }
#pragma unroll
    for (int fi = 0; fi < 8; ++fi)
#pragma unroll
        for (int r = 0; r < 4; ++r) {
            int row = bm + wm * 128 + fi * 16 + l4 * 4 + r;
            int t = inv[row];
            if (t >= 0) {
#pragma unroll
                for (int fj = 0; fj < 4; ++fj) {
                    int col = bn + wn * 64 + fj * 16 + l15;
                    store_c(C, (size_t)t * ldC + col, acc[fi][fj][r]);
                }
            }
        }
}

// ---------- RoPE in place; 8 pairs/thread; folds rsqrt(128)*log2e into Q ----------
__global__ void rope_kernel(u16* __restrict__ QKV, const float* __restrict__ fc) {
    int p8 = blockIdx.x * 256 + threadIdx.x;  // Tv*160 total (8 pairs each)
    const int t = p8 / 160;
    const int r8 = (p8 - t * 160) * 8;        // starting pair, multiple of 8
    const int s = t & (Sv - 1);
    int col, d2b; float scale;
    if (r8 < 1024) { col = 2 * r8;               d2b = r8 & 63;  scale = 0.12751742f; }
    else           { int rr = r8 - 1024; col = 2048 + 2 * rr; d2b = rr & 63; scale = 1.0f; }
    u16* ptr = QKV + (size_t)t * QKVN + col;
    u16x8 va = *(const u16x8*)ptr;
    u16x8 vb = *(const u16x8*)(ptr + 8);
    u16 arr[16];
#pragma unroll
    for (int i = 0; i < 8; ++i) { arr[i] = va[i]; arr[8 + i] = vb[i]; }
#pragma unroll
    for (int i = 0; i < 8; ++i) {
        float t0 = b2f(arr[2 * i]), t1 = b2f(arr[2 * i + 1]);
        f32x4u f = *(const f32x4u*)&fc[((size_t)s * 64 + d2b + i) * 4];  // [c,-s,s,c]
        arr[2 * i]     = f2b((t0 * f[0] + t1 * f[1]) * scale);
        arr[2 * i + 1] = f2b((t0 * f[2] + t1 * f[3]) * scale);
    }
#pragma unroll
    for (int i = 0; i < 8; ++i) { va[i] = arr[i]; vb[i] = arr[8 + i]; }
    *(u16x8*)ptr = va;
    *(u16x8*)(ptr + 8) = vb;
}

// ---------- causal GQA flash attention (R13-best: paired q-tiles, uniform work) ----------
// 8 waves: group 0 (waves 0-3) owns 64-row q-tile p, group 1 owns 31-p -> every block does
// exactly 32 stages + 33 group-computes (scheduler-independent balance, 2 blocks/CU).
// Swapped QK (q=l15) + permuted K rows (kv'(p) = (p&32)|((p&12)<<1)|((p&16)>>2)|(p&3)) so
// sacc[nt][r] = P[q][kv=(nt>>1)*32+l4*8+(nt&1)*4+r]; P-frags via 8x cvt_pk (no cross-lane).
// PV fully swapped -> O^T; transposed once in LDS epilogue. exp2-domain softmax.
// T5 setprio around MFMA clusters; T13 defer-max (THR=8).
__global__ __launch_bounds__(512) void attn_fwd(const u16* __restrict__ QKV, u16* __restrict__ Ag,
                                                const int* __restrict__ fwd) {
    const int p = blockIdx.x;                 // pair id 0..15
    const int h = blockIdx.y, b = blockIdx.z;
    const int kvh = h >> 2;
    const int tid = threadIdx.x, wave = tid >> 6, lane = tid & 63;
    const int wgrp = wave >> 2, wl = wave & 3;
    const int l15 = lane & 15, l4 = lane >> 4;
    const int myqb = wgrp ? (31 - p) : p;
    __shared__ u16 smem[32768];               // K dbuf @0/@8192, V dbuf @16384/@24576

    bf16x8 qf[4];
    {
        const size_t qrow = (size_t)(b * Sv + myqb * 64 + wl * 16 + l15);
#pragma unroll
        for (int kc = 0; kc < 4; ++kc)
            qf[kc] = *(const bf16x8*)&QKV[qrow * QKVN + h * 128 + kc * 32 + l4 * 8];
    }
    f32x4 oacc[8] = {};
    float mrow = -1e30f;   // running max (log2 domain) for q = l15
    float lrow = 0.f;

    const size_t kvbase = (size_t)b * Sv * QKVN + 2048 + kvh * 128;

    // ---- prologue: stage tile 0 ----
    {
#pragma unroll
        for (int i = 0; i < 2; ++i) {
            int s_u = wave * 64 + 512 * i;
            int s = s_u + lane;
            int r = s >> 4;                                   // LDS row
            int kvsrc = (r & 32) | ((r & 12) << 1) | ((r & 16) >> 2) | (r & 3);
            int cs = (s & 15) ^ (r & 7);
            gload_lds16(QKV + kvbase + (size_t)kvsrc * QKVN + cs * 8, &smem[(size_t)s_u * 8]);
        }
        u16x8 vr0 = *(const u16x8*)&QKV[kvbase + 512 + (size_t)lane * QKVN + (0 * 8 + wave) * 8];
        u16x8 vr1 = *(const u16x8*)&QKV[kvbase + 512 + (size_t)lane * QKVN + (1 * 8 + wave) * 8];
#pragma unroll
        for (int jj = 0; jj < 8; ++jj) {
            int d0 = wave * 8 + jj, d1 = (8 + wave) * 8 + jj;
            smem[16384 + d0 * 64 + ((((lane >> 3) ^ jj) << 3) | (lane & 7))] = vr0[jj];
            smem[16384 + d1 * 64 + ((((lane >> 3) ^ jj) << 3) | (lane & 7))] = vr1[jj];
        }
    }
    __syncthreads();

    for (int j = 0; j < 32; ++j) {
        const int cur = j & 1;
        const bool stage_next = (j < 31);
        u16* Kcur = smem + cur * 8192;
        u16* Knxt = smem + (cur ^ 1) * 8192;
        u16* Vcur = smem + 16384 + cur * 8192;
        u16* Vnxt = smem + 16384 + (cur ^ 1) * 8192;
        u16x8 vn0, vn1;
        if (stage_next) {
            const size_t nb = kvbase + (size_t)(j + 1) * 64 * QKVN;
#pragma unroll
            for (int i = 0; i < 2; ++i) {
                int s_u = wave * 64 + 512 * i;
                int s = s_u + lane;
                int r = s >> 4;
                int kvsrc = (r & 32) | ((r & 12) << 1) | ((r & 16) >> 2) | (r & 3);
                int cs = (s & 15) ^ (r & 7);
                gload_lds16(QKV + nb + (size_t)kvsrc * QKVN + cs * 8, &Knxt[(size_t)s_u * 8]);
            }
            vn0 = *(const u16x8*)&QKV[nb + 512 + (size_t)lane * QKVN + (0 * 8 + wave) * 8];
            vn1 = *(const u16x8*)&QKV[nb + 512 + (size_t)lane * QKVN + (1 * 8 + wave) * 8];
        }
        if (j <= myqb) {
            f32x4 sacc[4] = {};
            __builtin_amdgcn_s_setprio(1);
#pragma unroll
            for (int kc = 0; kc < 4; ++kc)
#pragma unroll
                for (int nt = 0; nt < 4; ++nt) {
                    int cs = ((kc * 4 + l4) ^ (l15 & 7));
                    bf16x8 kf = *(const bf16x8*)&Kcur[(nt * 16 + l15) * 128 + cs * 8];
                    sacc[nt] = __builtin_amdgcn_mfma_f32_16x16x32_bf16(kf, qf[kc], sacc[nt], 0, 0, 0);
                }
            __builtin_amdgcn_s_setprio(0);
            if (j == myqb) {
                // actual kv for sacc[nt][r] = (nt>>1)*32 + l4*8 + (nt&1)*4 + r
#pragma unroll
                for (int nt = 0; nt < 4; ++nt)
#pragma unroll
                    for (int r = 0; r < 4; ++r)
                        if ((nt >> 1) * 32 + l4 * 8 + (nt & 1) * 4 + r > wl * 16 + l15)
                            sacc[nt][r] = -1e30f;
            }
            // ---- lane-local online softmax (log2 domain) for q = l15 ----
            f32x4 mv = sacc[0];
#pragma unroll
            for (int nt = 1; nt < 4; ++nt)
#pragma unroll
                for (int r = 0; r < 4; ++r) mv[r] = fmaxf(mv[r], sacc[nt][r]);
            float mx = fmaxf(fmaxf(mv[0], mv[1]), fmaxf(mv[2], mv[3]));
            mx = fmaxf(mx, __shfl_xor(mx, 16, 64));
            mx = fmaxf(mx, __shfl_xor(mx, 32, 64));
            const bool defer = __all(mx <= mrow + 8.0f);
            if (!defer) {
                float mnew = fmaxf(mrow, mx);
                float fs = exp2f(mrow - mnew);
                mrow = mnew;
                lrow *= fs;
#pragma unroll
                for (int nt = 0; nt < 8; ++nt)
#pragma unroll
                    for (int r = 0; r < 4; ++r) oacc[nt][r] *= fs;
            }
            f32x4 pv = {0.f, 0.f, 0.f, 0.f};
#pragma unroll
            for (int nt = 0; nt < 4; ++nt)
#pragma unroll
                for (int r = 0; r < 4; ++r) {
                    float pe = exp2f(sacc[nt][r] - mrow);
                    sacc[nt][r] = pe;
                    pv[r] += pe;
                }
            float ps = (pv[0] + pv[1]) + (pv[2] + pv[3]);
            ps += __shfl_xor(ps, 16, 64);
            ps += __shfl_xor(ps, 32, 64);
            lrow += ps;
            // ---- P fragments in-register: 8x cvt_pk, zero cross-lane ----
            union { uint32_t w[4]; bf16x8 v; } pb0u, pb1u;
#pragma unroll
            for (int nt = 0; nt < 2; ++nt) {
                asm("v_cvt_pk_bf16_f32 %0, %1, %2" : "=v"(pb0u.w[nt * 2])     : "v"(sacc[nt][0]), "v"(sacc[nt][1]));
                asm("v_cvt_pk_bf16_f32 %0, %1, %2" : "=v"(pb0u.w[nt * 2 + 1]) : "v"(sacc[nt][2]), "v"(sacc[nt][3]));
                asm("v_cvt_pk_bf16_f32 %0, %1, %2" : "=v"(pb1u.w[nt * 2])     : "v"(sacc[nt + 2][0]), "v"(sacc[nt + 2][1]));
                asm("v_cvt_pk_bf16_f32 %0, %1, %2" : "=v"(pb1u.w[nt * 2 + 1]) : "v"(sacc[nt + 2][2]), "v"(sacc[nt + 2][3]));
            }
            bf16x8 pb0 = pb0u.v, pb1 = pb1u.v;
            // ---- PV: O^T += V^T * P^T ----
            __builtin_amdgcn_s_setprio(1);
#pragma unroll
            for (int nt = 0; nt < 8; ++nt) {
                int d = nt * 16 + l15;           // d&7 == l15&7
                bf16x8 v0 = *(const bf16x8*)&Vcur[d * 64 + ((l4 ^ (l15 & 7)) << 3)];
                bf16x8 v1 = *(const bf16x8*)&Vcur[d * 64 + (((4 + l4) ^ (l15 & 7)) << 3)];
                oacc[nt] = __builtin_amdgcn_mfma_f32_16x16x32_bf16(v0, pb0, oacc[nt], 0, 0, 0);
                oacc[nt] = __builtin_amdgcn_mfma_f32_16x16x32_bf16(v1, pb1, oacc[nt], 0, 0, 0);
            }
            __builtin_amdgcn_s_setprio(0);
        }
        if (stage_next) {
#pragma unroll
            for (int jj = 0; jj < 8; ++jj) {
                int d0 = wave * 8 + jj, d1 = (8 + wave) * 8 + jj;
                Vnxt[d0 * 64 + ((((lane >> 3) ^ jj) << 3) | (lane & 7))] = vn0[jj];
                Vnxt[d1 * 64 + ((((lane >> 3) ^ jj) << 3) | (lane & 7))] = vn1[jj];
            }
        }
        __syncthreads();
    }
    // ---- epilogue: transpose O^T -> token-major via per-wave LDS (K/V buffers dead) ----
    {
        u16* epi = smem + wave * (16 * 136);   // [16 q][128 d + 8 pad]
        float rinv = 1.0f / lrow;              // per lane q=l15
#pragma unroll
        for (int nt = 0; nt < 8; ++nt)
#pragma unroll
            for (int r = 0; r < 4; ++r)
                epi[l15 * 136 + nt * 16 + l4 * 4 + r] = f2b(oacc[nt][r] * rinv);
        const int q = lane >> 2;
        const int rowmap = fwd[b * Sv + myqb * 64 + wl * 16 + q];
#pragma unroll
        for (int it = 0; it < 4; ++it) {
            int dv = (lane & 3) + it * 4;
            u16x8 v = *(const u16x8*)&epi[q * 136 + dv * 8];
            *(u16x8*)&Ag[(size_t)rowmap * 2048 + h * 128 + dv * 8] = v;
        }
    }
}

extern "C" void kernel_launch(void* const* d_in, const int* in_sizes, int n_in,
                              void* d_out, int out_size, void* d_ws, size_t ws_size,
                              hipStream_t stream) {
    const float* x   = (const float*)d_in[0];
    const float* fc  = (const float*)d_in[1];
    const int*   mod = (const int*)d_in[2];
    const float* wq  = (const float*)d_in[3];
    const float* wk  = (const float*)d_in[4];
    const float* wv  = (const float*)d_in[5];
    const float* wo  = (const float*)d_in[6];
    float* out = (float*)d_out;
    char* ws = (char*)d_ws;
    u16* Wqkv_t = (u16*)(ws);               // 2 x (3072 x 2048) bf16 = 25,165,824
    u16* Wo_t   = (u16*)(ws + 25165824);    // 2 x (2048 x 2048) bf16 = 16,777,216
    u16* Xg     = (u16*)(ws + 41943040);    // MAXROWS x 2048 bf16 = 17,825,792 (reused as Ag)
    u16* QKV    = (u16*)(ws + 59768832);    // 4096 x 3072 bf16 = 25,165,824
    int* fwd    = (int*)(ws + 84934656);    // 4096 ints
    int* inv    = (int*)(ws + 84951040);    // MAXROWS ints
    int* hdr    = (int*)(ws + 84968448);    // small header
    u16* Ag     = Xg;                        // Xg dead after QKV GEMM; pads stay zero from gather_cast

    transpose_all<<<5120, 256, 0, stream>>>(wq, wk, wv, wo, Wqkv_t, Wo_t);
    scan_mod<<<1, 1024, 0, stream>>>(mod, fwd, inv, hdr);
    gather_cast<<<MAXROWS, 256, 0, stream>>>(x, inv, Xg);
    gemm256<u16><<<dim3(12, 17), 512, 0, stream>>>(Xg, Wqkv_t, QKV, inv, hdr, 3072, 3072);
    rope_kernel<<<2560, 256, 0, stream>>>(QKV, fc);
    attn_fwd<<<dim3(16, 16, 2), 512, 0, stream>>>(QKV, Ag, fwd);
    gemm256<float><<<dim3(8, 17), 512, 0, stream>>>(Ag, Wo_t, out, inv, hdr, 2048, 2048);
}